// Round 3
// baseline (56.835 us; speedup 1.0000x reference)
//
#include <hip/hip_runtime.h>

// MeanAggregator: out[n, :] = (1/K) * sum_{k<K} features[idx[n,k], :]
// N=100000, K=6, V=200000, D=128, fp32.
//
// Round 3: same as round 2, but use a clang native vector type for the
// non-temporal store (HIP float4 is a struct and the builtin rejects it).
//
// Layout: 32 lanes per node, lane owns one f32x4 (16B) of the 512B row.
// 256 threads/block -> 8 node-slots/block; grid = 2048 blocks (8/CU).

typedef float f32x4 __attribute__((ext_vector_type(4)));

#define K_NEIGH 6
#define D_FEAT 128
#define NODES_PER_BLOCK 8

__global__ __launch_bounds__(256) void MeanAggregator_16415365005349_kernel(
    const float* __restrict__ feat,
    const int* __restrict__ idx,
    float* __restrict__ out,
    int N) {
  const int slot = threadIdx.x >> 5;   // 0..7
  const int lane = threadIdx.x & 31;
  const int stride = gridDim.x * NODES_PER_BLOCK;

  int node = blockIdx.x * NODES_PER_BLOCK + slot;

  // Prologue: fetch indices for the first node.
  int r[K_NEIGH];
  if (node < N) {
#pragma unroll
    for (int k = 0; k < K_NEIGH; ++k) r[k] = idx[(size_t)node * K_NEIGH + k];
  }

  while (node < N) {
    const int next = node + stride;

    // Issue all 6 row gathers back-to-back (independent, in flight together).
    f32x4 v[K_NEIGH];
#pragma unroll
    for (int k = 0; k < K_NEIGH; ++k) {
      v[k] = reinterpret_cast<const f32x4*>(feat + (size_t)r[k] * D_FEAT)[lane];
    }

    // Prefetch next iteration's indices while the gathers are in flight
    // (no dependency on v[], so these issue before the vmcnt wait on v[]).
    int rn[K_NEIGH];
    if (next < N) {
#pragma unroll
      for (int k = 0; k < K_NEIGH; ++k) rn[k] = idx[(size_t)next * K_NEIGH + k];
    }

    f32x4 acc = v[0];
#pragma unroll
    for (int k = 1; k < K_NEIGH; ++k) acc += v[k];
    acc *= (1.0f / (float)K_NEIGH);

    // Non-temporal store: output is write-once, keep it out of L2/L3.
    f32x4* dst = reinterpret_cast<f32x4*>(out + (size_t)node * D_FEAT) + lane;
    __builtin_nontemporal_store(acc, dst);

#pragma unroll
    for (int k = 0; k < K_NEIGH; ++k) r[k] = rn[k];
    node = next;
  }
}

extern "C" void kernel_launch(void* const* d_in, const int* in_sizes, int n_in,
                              void* d_out, int out_size, void* d_ws, size_t ws_size,
                              hipStream_t stream) {
  const float* feat = (const float*)d_in[0];   // [V, D] fp32
  const int* idx = (const int*)d_in[1];        // [N, K] int32 (harness-cast)
  float* out = (float*)d_out;                  // [N, D] fp32

  const int N = in_sizes[1] / K_NEIGH;         // 100000

  // Persistent-ish grid: 8 blocks/CU * 256 CUs.
  const int max_blocks = 2048;
  int blocks = (N + NODES_PER_BLOCK - 1) / NODES_PER_BLOCK;
  if (blocks > max_blocks) blocks = max_blocks;

  hipLaunchKernelGGL(MeanAggregator_16415365005349_kernel,
                     dim3(blocks), dim3(256), 0, stream,
                     feat, idx, out, N);
}